// Round 10
// baseline (22.320 us; speedup 1.0000x reference)
//
#include <hip/hip_runtime.h>

// SimpleCNN forward, mathematically simplified (validated rounds 1-9):
//   out = fc( pool(relu(s*conv2+b2)( pool(relu(s*conv1+b1)(x)) )) ),  s = 1/(1+1e-5)
// Round 10: 2 blocks per sample (split conv2 by oc-half) -> 1024 blocks,
// 4 blocks/CU, 16 waves/CU (was 8): attacks the latency-bound gap
// (ideal-issue body ~2-3us vs measured 15.9us).
//  - each half-block: full conv1 (duplicated), half swr (16 oc), half-M conv2
//    (5 MFMA/tile), half pool, contiguous fc partial (fcw offset h*784,
//    float4-aligned).
//  - halves combine via one atomicAdd per (n,j); exactly 2 contributions and
//    2-operand f32 add is commutative bitwise -> deterministic. d_out zeroed
//    per call via hipMemsetAsync (graph-legal).
//  - s_setprio(1) around MFMA cluster (blocks at diverse phases on a CU).

typedef __fp16 h2v __attribute__((ext_vector_type(2)));
typedef __fp16 h8  __attribute__((ext_vector_type(8)));
typedef float  f4  __attribute__((ext_vector_type(4)));

__device__ __forceinline__ unsigned as_u32(h2v h) {
    union { unsigned u; h2v h; } x; x.h = h; return x.u;
}
__device__ __forceinline__ h8 ld_h8(const unsigned* p) {
    union { uint4 u; h8 h; } v; v.u = *(const uint4*)p; return v.h;
}

__global__ __launch_bounds__(256, 4) void fused_cnn(
    const float* __restrict__ x,     // (512,1,28,28)
    const float* __restrict__ w1,    // (16,1,3,3)
    const float* __restrict__ b1,    // (16,)
    const float* __restrict__ w2,    // (32,16,3,3)
    const float* __restrict__ b2,    // (32,)
    const float* __restrict__ fcw,   // (10,1568)
    const float* __restrict__ fcb,   // (10,)
    float* __restrict__ out)         // (512,10), pre-zeroed
{
    const int n = blockIdx.x >> 1;
    const int h = blockIdx.x & 1;          // oc-half: oc 16h .. 16h+15
    const int t = threadIdx.x;
    const float s = (float)(1.0 / 1.00001);   // 1/(1+TEMP)

    // union: phase0/1 = [sx 1080 f32 | raw half-w2 2304 u32], phase2+ = Dl [16][197]
    __shared__ float    uni[3384];
    __shared__ unsigned sh1[2 * 18 * 16 * 4];  // h1 HWC f16 (full): [cg][row][xcol][4 u32]
    __shared__ unsigned swr[16 * 84];          // half w2 reordered: [ocl][84 u32]
    __shared__ float    sh2[16 * 49];          // this half's pooled output
    __shared__ float    sb2[16];

    float*    sx  = uni;                       // 1080 floats
    unsigned* raw = (unsigned*)(uni + 1080);   // 2304 u32 (byte off 4320, 16B-aligned)
    float*    Dl  = uni;                       // [16][197] (conv2 phase)

    // ---- phase 0: stage (vectorized zero-init) ----
    {
        float4* sxz = (float4*)sx;
        for (int i = t; i < 270; i += 256) sxz[i] = float4{0.f, 0.f, 0.f, 0.f};
        uint4* shz = (uint4*)sh1;
        for (int i = t; i < 576; i += 256) shz[i] = uint4{0u, 0u, 0u, 0u};
    }
    if (t < 196) {
        const float4 v = ((const float4*)(x + n * 784))[t];
        const int r = t / 7, c4 = (t - r * 7) * 4;
        float* dst = &sx[(r + 1) * 36 + c4 + 1];
        dst[0] = v.x; dst[1] = v.y; dst[2] = v.z; dst[3] = v.w;
    }
    {   // coalesced raw half-w2 copy: 576 uint4
        uint4* rawv = (uint4*)raw;
        const uint4* w2v = (const uint4*)w2 + h * 576;
        for (int i = t; i < 576; i += 256) rawv[i] = w2v[i];
    }
    if (t < 128) {  // zero swr K-pad tail (entries 72..79 per local oc)
        const int oc = t >> 3;
        swr[oc * 84 + 72 + (t & 7)] = 0u;
    }
    if (t < 16) sb2[t] = b2[h * 16 + t];
    __syncthreads();

    // ---- phase 1: swr convert (LDS->LDS, local oc) + conv1 (full, duplicated) ----
    for (int i = t; i < 1152; i += 256) {      // build swr (k=(ki,kj,c))
        const int oc = i / 72, r = i - oc * 72;
        const int ki = r / 24, r2 = r - ki * 24, kj = r2 >> 3, c = 2 * (r2 & 7);
        const float a = __uint_as_float(raw[(oc * 16 + c) * 9 + ki * 3 + kj]);
        const float b = __uint_as_float(raw[(oc * 16 + c + 1) * 9 + ki * 3 + kj]);
        swr[oc * 84 + r] = as_u32(__builtin_amdgcn_cvt_pkrtz(a, b));
    }
    {
        const int ocp = t & 7;                 // conv1 out-ch pair (2ocp, 2ocp+1)
        float wa[9], wb[9];
        #pragma unroll
        for (int k = 0; k < 9; ++k) { wa[k] = w1[ocp * 18 + k]; wb[k] = w1[ocp * 18 + 9 + k]; }
        const float ba = b1[2 * ocp], bb = b1[2 * ocp + 1];
        const int cg = ocp >> 2, slot = ocp & 3;

        for (int p = t >> 3; p < 98; p += 32) {
            const int row = p / 7;
            const int pcp = p - row * 7;
            float pr[4][6];
            const float* base = &sx[(2 * row) * 36 + 4 * pcp];
            #pragma unroll
            for (int rr = 0; rr < 4; ++rr) {
                const float4 a4 = *(const float4*)(base + rr * 36);
                const float2 a2 = *(const float2*)(base + rr * 36 + 4);
                pr[rr][0] = a4.x; pr[rr][1] = a4.y; pr[rr][2] = a4.z; pr[rr][3] = a4.w;
                pr[rr][4] = a2.x; pr[rr][5] = a2.y;
            }
            float va[2][4], vb[2][4];
            #pragma unroll
            for (int cr = 0; cr < 2; ++cr)
                #pragma unroll
                for (int cc = 0; cc < 4; ++cc) {
                    float a = 0.0f, b = 0.0f;
                    #pragma unroll
                    for (int ki = 0; ki < 3; ++ki)
                        #pragma unroll
                        for (int kj = 0; kj < 3; ++kj) {
                            const float pv = pr[cr + ki][cc + kj];
                            a = fmaf(wa[ki * 3 + kj], pv, a);
                            b = fmaf(wb[ki * 3 + kj], pv, b);
                        }
                    va[cr][cc] = a; vb[cr][cc] = b;
                }
            #pragma unroll
            for (int d = 0; d < 2; ++d) {
                const float ma = fmaxf(fmaxf(va[0][2 * d], va[0][2 * d + 1]),
                                       fmaxf(va[1][2 * d], va[1][2 * d + 1]));
                const float mb = fmaxf(fmaxf(vb[0][2 * d], vb[0][2 * d + 1]),
                                       fmaxf(vb[1][2 * d], vb[1][2 * d + 1]));
                const float pa = fmaxf(fmaf(s, ma, ba), 0.0f);
                const float pb = fmaxf(fmaf(s, mb, bb), 0.0f);
                const int xc = 2 * pcp + d + 1;         // padded col
                sh1[((cg * 18 + row + 1) * 16 + xc) * 4 + slot] =
                    as_u32(__builtin_amdgcn_cvt_pkrtz(pa, pb));
            }
        }
    }
    __syncthreads();

    // ---- phase 2: half-M conv2 GEMM: D[16 oc][196 pix] = W[16][160] * P[160][pix] ----
    {
        const int lane = t & 63, wv = t >> 6;
        const int l15 = lane & 15, kgrp = lane >> 4;
        // A-fragments: lane holds W[oc = l15][k = 32s + 8*kgrp .. +8]
        h8 afr[5];
        #pragma unroll
        for (int ss = 0; ss < 5; ++ss)
            afr[ss] = ld_h8(&swr[l15 * 84 + 16 * ss + 4 * kgrp]);

        const int khi = kgrp >> 1, cgl = kgrp & 1;   // tap-offset, ch-granule
        for (int nt = wv; nt < 13; nt += 4) {        // N-tiles of 16 pixels
            const int p = 16 * nt + l15;             // pixel (col); >=196 = padding
            const int y = p / 14, x2 = p - 14 * y;
            h8 bfr[5];
            #pragma unroll
            for (int ss = 0; ss < 5; ++ss) {
                const int tt = 2 * ss + khi;         // tap 0..9 (9 = K-pad, A=0)
                const int ki = tt / 3, kj = tt - 3 * ki;
                const int g = (cgl * 18 + y + ki) * 16 + (x2 + kj);  // 16B granule
                bfr[ss] = ld_h8(&sh1[g * 4]);
            }
            f4 d0 = {0.f, 0.f, 0.f, 0.f};
            __builtin_amdgcn_s_setprio(1);
            #pragma unroll
            for (int ss = 0; ss < 5; ++ss)
                d0 = __builtin_amdgcn_mfma_f32_16x16x32_f16(afr[ss], bfr[ss], d0, 0, 0, 0);
            __builtin_amdgcn_s_setprio(0);
            if (p < 196) {
                #pragma unroll
                for (int r = 0; r < 4; ++r)          // D row = local oc = kgrp*4 + r
                    Dl[(kgrp * 4 + r) * 197 + p] = d0[r];
            }
        }
    }
    __syncthreads();

    // ---- phase 3: pool + relu + scale -> sh2 (this half's 16 oc) ----
    for (int item = t; item < 784; item += 256) {
        const int oc = item / 49, q = item - oc * 49;
        const int py = q / 7, px = q - py * 7;
        const float* dp = &Dl[oc * 197 + 28 * py + 2 * px];
        const float m = fmaxf(fmaxf(dp[0], dp[1]), fmaxf(dp[14], dp[15]));
        sh2[item] = fmaxf(fmaf(s, m, sb2[oc]), 0.0f);
    }
    __syncthreads();

    // ---- phase 4: fc partial (contiguous half of fcw), atomicAdd combine ----
    {
        const int wv = t >> 6, lane = t & 63;
        const float4* sh2v = (const float4*)sh2;            // 196 float4
        const float4* fcwv = (const float4*)fcw;
        for (int j = wv; j < 10; j += 4) {
            float part = 0.0f;
            for (int i = lane; i < 196; i += 64) {
                const float4 hh = sh2v[i];
                const float4 wq = fcwv[j * 392 + h * 196 + i];
                part = fmaf(hh.x, wq.x, fmaf(hh.y, wq.y,
                       fmaf(hh.z, wq.z, fmaf(hh.w, wq.w, part))));
            }
            #pragma unroll
            for (int off = 32; off > 0; off >>= 1) part += __shfl_down(part, off);
            if (lane == 0) {
                const float v = part + (h == 0 ? fcb[j] : 0.0f);
                atomicAdd(&out[n * 10 + j], v);
            }
        }
    }
}

extern "C" void kernel_launch(void* const* d_in, const int* in_sizes, int n_in,
                              void* d_out, int out_size, void* d_ws, size_t ws_size,
                              hipStream_t stream) {
    const float* x   = (const float*)d_in[0];
    const float* w1  = (const float*)d_in[1];
    const float* b1  = (const float*)d_in[2];
    const float* w2  = (const float*)d_in[3];
    const float* b2  = (const float*)d_in[4];
    const float* fcw = (const float*)d_in[5];
    const float* fcb = (const float*)d_in[6];
    float* out = (float*)d_out;

    hipMemsetAsync(out, 0, (size_t)out_size * sizeof(float), stream);
    fused_cnn<<<1024, 256, 0, stream>>>(x, w1, b1, w2, b2, fcw, fcb, out);
}

// Round 11
// 14.511 us; speedup vs baseline: 1.5382x; 1.5382x over previous
//
#include <hip/hip_runtime.h>

// SimpleCNN forward, mathematically simplified (validated rounds 1-9):
//   out = fc( pool(relu(s*conv2+b2)( pool(relu(s*conv1+b1)(x)) )) ),  s = 1/(1+1e-5)
// Round 11: round-9 structure, 512 threads/block (8 waves, 1 sample/block).
// Same per-CU DS work (no duplication — the round-10 mistake), but every
// phase's critical path ~halves: conv2 13 tiles / 8 waves, conv1 98 pos /
// 64 groups, pool 3 iters, fc 10 j / 8 waves.

typedef __fp16 h2v __attribute__((ext_vector_type(2)));
typedef __fp16 h8  __attribute__((ext_vector_type(8)));
typedef float  f4  __attribute__((ext_vector_type(4)));

__device__ __forceinline__ unsigned as_u32(h2v h) {
    union { unsigned u; h2v h; } x; x.h = h; return x.u;
}
__device__ __forceinline__ h8 ld_h8(const unsigned* p) {
    union { uint4 u; h8 h; } v; v.u = *(const uint4*)p; return v.h;
}

__global__ __launch_bounds__(512, 2) void fused_cnn(
    const float* __restrict__ x,     // (512,1,28,28)
    const float* __restrict__ w1,    // (16,1,3,3)
    const float* __restrict__ b1,    // (16,)
    const float* __restrict__ w2,    // (32,16,3,3)
    const float* __restrict__ b2,    // (32,)
    const float* __restrict__ fcw,   // (10,1568)
    const float* __restrict__ fcb,   // (10,)
    float* __restrict__ out)         // (512,10)
{
    const int n = blockIdx.x;
    const int t = threadIdx.x;
    const float s = (float)(1.0 / 1.00001);   // 1/(1+TEMP)

    // union: phase0/1 = [sx 1080 f32 | raw w2 4608 u32], phase2+ = Dl [32][197] f32
    __shared__ float    uni[32 * 197];
    __shared__ unsigned sh1[2 * 18 * 16 * 4];  // h1 HWC f16: [cg][row][xcol][4 u32]
    __shared__ unsigned swr[32 * 84];          // w2 reordered: [oc][84 u32] (K 160 f16)
    __shared__ float    sh2[1568];             // (32,7,7)
    __shared__ float    sb2[32];

    float*    sx  = uni;                       // 1080 floats
    unsigned* raw = (unsigned*)(uni + 1080);   // 4608 u32
    float*    Dl  = uni;                       // [oc][197] (conv2 phase)

    // ---- phase 0: stage (vectorized zero-init) ----
    {
        float4* sxz = (float4*)sx;
        for (int i = t; i < 270; i += 512) sxz[i] = float4{0.f, 0.f, 0.f, 0.f};
        uint4* shz = (uint4*)sh1;
        for (int i = t; i < 576; i += 512) shz[i] = uint4{0u, 0u, 0u, 0u};
    }
    if (t < 196) {
        const float4 v = ((const float4*)(x + n * 784))[t];
        const int r = t / 7, c4 = (t - r * 7) * 4;
        float* dst = &sx[(r + 1) * 36 + c4 + 1];
        dst[0] = v.x; dst[1] = v.y; dst[2] = v.z; dst[3] = v.w;
    }
    {   // coalesced raw w2 copy: 1152 uint4
        uint4* rawv = (uint4*)raw;
        const uint4* w2v = (const uint4*)w2;
        for (int i = t; i < 1152; i += 512) rawv[i] = w2v[i];
    }
    if (t < 256) {  // zero swr K-pad tail (entries 72..79 per oc)
        const int oc = t >> 3;
        swr[oc * 84 + 72 + (t & 7)] = 0u;
    }
    if (t < 32) sb2[t] = b2[t];
    __syncthreads();

    // ---- phase 1: swr convert (LDS->LDS) + conv1 ----
    for (int i = t; i < 2304; i += 512) {      // build swr (k=(ki,kj,c))
        const int oc = i / 72, r = i - oc * 72;
        const int ki = r / 24, r2 = r - ki * 24, kj = r2 >> 3, c = 2 * (r2 & 7);
        const float a = __uint_as_float(raw[(oc * 16 + c) * 9 + ki * 3 + kj]);
        const float b = __uint_as_float(raw[(oc * 16 + c + 1) * 9 + ki * 3 + kj]);
        swr[oc * 84 + r] = as_u32(__builtin_amdgcn_cvt_pkrtz(a, b));
    }
    {
        const int ocp = t & 7;                 // out-ch pair (2ocp, 2ocp+1)
        float wa[9], wb[9];
        #pragma unroll
        for (int k = 0; k < 9; ++k) { wa[k] = w1[ocp * 18 + k]; wb[k] = w1[ocp * 18 + 9 + k]; }
        const float ba = b1[2 * ocp], bb = b1[2 * ocp + 1];
        const int cg = ocp >> 2, slot = ocp & 3;

        for (int p = t >> 3; p < 98; p += 64) {
            const int row = p / 7;
            const int pcp = p - row * 7;
            float pr[4][6];
            const float* base = &sx[(2 * row) * 36 + 4 * pcp];
            #pragma unroll
            for (int rr = 0; rr < 4; ++rr) {
                const float4 a4 = *(const float4*)(base + rr * 36);
                const float2 a2 = *(const float2*)(base + rr * 36 + 4);
                pr[rr][0] = a4.x; pr[rr][1] = a4.y; pr[rr][2] = a4.z; pr[rr][3] = a4.w;
                pr[rr][4] = a2.x; pr[rr][5] = a2.y;
            }
            float va[2][4], vb[2][4];
            #pragma unroll
            for (int cr = 0; cr < 2; ++cr)
                #pragma unroll
                for (int cc = 0; cc < 4; ++cc) {
                    float a = 0.0f, b = 0.0f;
                    #pragma unroll
                    for (int ki = 0; ki < 3; ++ki)
                        #pragma unroll
                        for (int kj = 0; kj < 3; ++kj) {
                            const float pv = pr[cr + ki][cc + kj];
                            a = fmaf(wa[ki * 3 + kj], pv, a);
                            b = fmaf(wb[ki * 3 + kj], pv, b);
                        }
                    va[cr][cc] = a; vb[cr][cc] = b;
                }
            #pragma unroll
            for (int d = 0; d < 2; ++d) {
                const float ma = fmaxf(fmaxf(va[0][2 * d], va[0][2 * d + 1]),
                                       fmaxf(va[1][2 * d], va[1][2 * d + 1]));
                const float mb = fmaxf(fmaxf(vb[0][2 * d], vb[0][2 * d + 1]),
                                       fmaxf(vb[1][2 * d], vb[1][2 * d + 1]));
                const float pa = fmaxf(fmaf(s, ma, ba), 0.0f);
                const float pb = fmaxf(fmaf(s, mb, bb), 0.0f);
                const int xc = 2 * pcp + d + 1;         // padded col
                sh1[((cg * 18 + row + 1) * 16 + xc) * 4 + slot] =
                    as_u32(__builtin_amdgcn_cvt_pkrtz(pa, pb));
            }
        }
    }
    __syncthreads();

    // ---- phase 2: conv2 implicit GEMM: D[32 oc][196 pix] = W[32][160] * P[160][pix] ----
    {
        const int lane = t & 63, wv = t >> 6;      // 8 waves
        const int l15 = lane & 15, kgrp = lane >> 4;
        // A-fragments: lane holds W[oc = m*16 + l15][k = 32s + 8*kgrp .. +8]
        h8 afr[2][5];
        #pragma unroll
        for (int m = 0; m < 2; ++m)
            #pragma unroll
            for (int ss = 0; ss < 5; ++ss)
                afr[m][ss] = ld_h8(&swr[(m * 16 + l15) * 84 + 16 * ss + 4 * kgrp]);

        const int khi = kgrp >> 1, cgl = kgrp & 1;   // tap-offset, ch-granule
        for (int nt = wv; nt < 13; nt += 8) {        // N-tiles of 16 pixels
            const int p = 16 * nt + l15;             // pixel (col); >=196 = padding
            const int y = p / 14, x2 = p - 14 * y;
            h8 bfr[5];
            #pragma unroll
            for (int ss = 0; ss < 5; ++ss) {
                const int tt = 2 * ss + khi;         // tap 0..9 (9 = K-pad, A=0)
                const int ki = tt / 3, kj = tt - 3 * ki;
                const int g = (cgl * 18 + y + ki) * 16 + (x2 + kj);  // 16B granule
                bfr[ss] = ld_h8(&sh1[g * 4]);
            }
            f4 d0 = {0.f, 0.f, 0.f, 0.f}, d1 = {0.f, 0.f, 0.f, 0.f};
            #pragma unroll
            for (int ss = 0; ss < 5; ++ss) {
                d0 = __builtin_amdgcn_mfma_f32_16x16x32_f16(afr[0][ss], bfr[ss], d0, 0, 0, 0);
                d1 = __builtin_amdgcn_mfma_f32_16x16x32_f16(afr[1][ss], bfr[ss], d1, 0, 0, 0);
            }
            if (p < 196) {
                #pragma unroll
                for (int r = 0; r < 4; ++r) {        // D row = oc = m*16 + kgrp*4 + r
                    Dl[(kgrp * 4 + r) * 197 + p]      = d0[r];
                    Dl[(16 + kgrp * 4 + r) * 197 + p] = d1[r];
                }
            }
        }
    }
    __syncthreads();

    // ---- phase 3: pool + relu + scale -> sh2 ----
    for (int item = t; item < 1568; item += 512) {
        const int oc = item / 49, q = item - oc * 49;
        const int py = q / 7, px = q - py * 7;
        const float* dp = &Dl[oc * 197 + 28 * py + 2 * px];
        const float m = fmaxf(fmaxf(dp[0], dp[1]), fmaxf(dp[14], dp[15]));
        sh2[item] = fmaxf(fmaf(s, m, sb2[oc]), 0.0f);
    }
    __syncthreads();

    // ---- phase 4: fc, wave-per-j (no barrier, no sred) ----
    {
        const int wv = t >> 6, lane = t & 63;
        const float4* sh2v = (const float4*)sh2;
        const float4* fcwv = (const float4*)fcw;
        for (int j = wv; j < 10; j += 8) {
            float part = 0.0f;
            for (int i = lane; i < 392; i += 64) {
                const float4 h  = sh2v[i];
                const float4 wq = fcwv[j * 392 + i];
                part = fmaf(h.x, wq.x, fmaf(h.y, wq.y,
                       fmaf(h.z, wq.z, fmaf(h.w, wq.w, part))));
            }
            #pragma unroll
            for (int off = 32; off > 0; off >>= 1) part += __shfl_down(part, off);
            if (lane == 0) out[n * 10 + j] = part + fcb[j];
        }
    }
}

extern "C" void kernel_launch(void* const* d_in, const int* in_sizes, int n_in,
                              void* d_out, int out_size, void* d_ws, size_t ws_size,
                              hipStream_t stream) {
    const float* x   = (const float*)d_in[0];
    const float* w1  = (const float*)d_in[1];
    const float* b1  = (const float*)d_in[2];
    const float* w2  = (const float*)d_in[3];
    const float* b2  = (const float*)d_in[4];
    const float* fcw = (const float*)d_in[5];
    const float* fcb = (const float*)d_in[6];
    float* out = (float*)d_out;

    fused_cnn<<<512, 512, 0, stream>>>(x, w1, b1, w2, b2, fcw, fcb, out);
}